// Round 14
// baseline (206.644 us; speedup 1.0000x reference)
//
#include <hip/hip_runtime.h>
#include <math.h>

#define B_ 8
#define T_ 64
#define N_ 196
#define D_ 768
#define K_ 8
#define FEAT 40
#define EPSF 1e-6f

constexpr int BN = B_ * N_;                        // 1568
constexpr int ROWS = B_ * T_ * N_;                 // 100352
constexpr long long HSIZE = (long long)ROWS * D_;  // 77070336
constexpr int QPR = D_ / 4;                        // 192 float4 per row
constexpr unsigned RSTRIDE = (unsigned)N_ * QPR;   // 37632 v4f per t-step
constexpr unsigned TSTRIDE = 4 * RSTRIDE;

typedef float v4f __attribute__((ext_vector_type(4)));

__device__ __forceinline__ float wredux(float v) {
#pragma unroll
    for (int off = 32; off > 0; off >>= 1)
        v += __shfl_xor(v, off, 64);
    return v;
}

__device__ __forceinline__ float dot4(v4f a, v4f b) {
    return a.x * b.x + a.y * b.y + a.z * b.z + a.w * b.w;
}

// W = softplus(W_raw) -> d_out tail;  beta_s = sigmoid(beta) -> ws
__global__ __launch_bounds__(256) void k_wsp(const float* __restrict__ wraw,
                                             const float* __restrict__ beta,
                                             float* __restrict__ wout,
                                             float* __restrict__ beta_s) {
    int i = blockIdx.x * blockDim.x + threadIdx.x;
    if (i < FEAT * D_) {
        float xw = wraw[i];
        wout[i] = fmaxf(xw, 0.0f) + log1pf(expf(-fabsf(xw)));
    }
    if (i < D_) beta_s[i] = 1.0f / (1.0f + expf(-beta[i]));
}

// Two columns per block: A(c0) | B/C(c0) | A(c1)∥D(c0) | B/C(c1) | D(c1).
// The fused middle keeps read AND write streams busy simultaneously
// (round-12 limiter: barrier-phased blocks left each stream idle ~half
// the time). No launch_bounds min-waves — allocator's natural 56-72 regs
// is the sweet spot (round-13 lesson: forcing 32 destroys the pipeline).
__global__ __launch_bounds__(256)
void k_fused(const float* __restrict__ x,
             const float* __restrict__ mask,
             const float* __restrict__ pw,
             const float* __restrict__ wsp,
             const float* __restrict__ beta_s,
             float* __restrict__ h) {
    __shared__ v4f   xbuf[2][4][QPR];     // 24 KB x tile double-buffer
    __shared__ float vpart[T_][K_ + 1];   // pad: odd stride, conflict-free
    __shared__ float sf[FEAT];
    __shared__ float ylds[2][D_];         // 6 KB: beta_s*y for c0 and c1
    __shared__ float smask[2][T_];

    const int tid  = threadIdx.x;
    const int lane = tid & 63;
    const int w    = tid >> 6;
    const int c0   = 2 * blockIdx.x;
    const int c1   = c0 + 1;
    const int b0   = c0 / N_, n0 = c0 - b0 * N_;
    const int b1   = c1 / N_, n1 = c1 - b1 * N_;

    // u-slice for this wave's two k's: 6 v4f = 24 VGPRs, loop-invariant
    v4f u[2][3];
#pragma unroll
    for (int kk = 0; kk < 2; kk++)
#pragma unroll
        for (int c = 0; c < 3; c++)
            u[kk][c] = *(const v4f*)(pw + (2 * w + kk) * D_ + c * 256 + lane * 4);

    if (tid < T_) {
        smask[0][tid] = mask[(b0 * T_ + tid) * N_ + n0];
        smask[1][tid] = mask[(b1 * T_ + tid) * N_ + n1];
    }

    const v4f* x4 = (const v4f*)x;
    v4f* h4 = (v4f*)h;
    const unsigned qbase0 = (unsigned)((b0 * T_) * N_ + n0) * QPR;
    const unsigned qbase1 = (unsigned)((b1 * T_) * N_ + n1) * QPR;

    // ================= A(c0): 16 tiles, double-buffered =================
    unsigned q = qbase0 + w * RSTRIDE;
    v4f R0 = x4[q + lane], R1 = x4[q + 64 + lane], R2 = x4[q + 128 + lane];
    xbuf[0][w][lane]       = R0;
    xbuf[0][w][64 + lane]  = R1;
    xbuf[0][w][128 + lane] = R2;
    __syncthreads();
    int p = 0;
#pragma unroll 1
    for (int tile = 0; tile < 16; ++tile) {
        if (tile < 15) {
            q += TSTRIDE;
            R0 = x4[q + lane];
            R1 = x4[q + 64 + lane];
            R2 = x4[q + 128 + lane];
        }
#pragma unroll
        for (int r = 0; r < 4; ++r) {
            v4f c0v = xbuf[p][r][lane];
            v4f c1v = xbuf[p][r][64 + lane];
            v4f c2v = xbuf[p][r][128 + lane];
            float a0 = dot4(c0v, u[0][0]) + dot4(c1v, u[0][1]) + dot4(c2v, u[0][2]);
            float a1 = dot4(c0v, u[1][0]) + dot4(c1v, u[1][1]) + dot4(c2v, u[1][2]);
            a0 += __shfl_xor(a0, 1, 64);
            a1 += __shfl_xor(a1, 1, 64);
            float val = (lane & 1) ? a1 : a0;
            val += __shfl_xor(val, 2, 64);
            val += __shfl_xor(val, 4, 64);
            val += __shfl_xor(val, 8, 64);
            val += __shfl_xor(val, 16, 64);
            val += __shfl_xor(val, 32, 64);
            if (lane < 2) vpart[tile * 4 + r][2 * w + lane] = val;
        }
        if (tile < 15) {
            xbuf[p ^ 1][w][lane]       = R0;
            xbuf[p ^ 1][w][64 + lane]  = R1;
            xbuf[p ^ 1][w][128 + lane] = R2;
        }
        __syncthreads();
        p ^= 1;
    }

    // prefetch c1 tile-0 row w now; lands during B/C(c0)
    q = qbase1 + w * RSTRIDE;
    R0 = x4[q + lane]; R1 = x4[q + 64 + lane]; R2 = x4[q + 128 + lane];

    // ================= B(c0) -> sf =================
#pragma unroll
    for (int kk = 0; kk < 2; kk++) {
        const int k = w + kk * 4;
        float v = vpart[lane][k] * smask[0][lane];
        float s2  = wredux(v * v);
        float rms = sqrtf(s2 * (1.0f / T_) + EPSF);
        float vb  = 2.5f * tanhf(v / (rms + EPSF));
        const float PI = 3.14159265358979323846f;
        float ph = PI * ((float)lane + 0.5f) / (float)T_;
        float cc1 = cosf(ph), cc2 = cosf(2.0f * ph);
        float nn1 = wredux(cc1 * cc1), nn2 = wredux(cc2 * cc2);
        float S1 = wredux(vb), Sc1 = wredux(vb * cc1);
        float Sc2 = wredux(vb * cc2), Sq = wredux(vb * vb);
        if (lane == 0) {
            float* o = sf + k * 5;
            o[0] = S1 / (8.0f + EPSF);
            o[1] = Sc1 / (sqrtf(nn1) + EPSF);
            o[2] = Sc2 / (sqrtf(nn2) + EPSF);
            o[3] = S1 * (1.0f / T_);
            o[4] = sqrtf(Sq * (1.0f / T_) + EPSF);
        }
    }
    __syncthreads();

    // ================= C(c0) -> ylds[0] =================
    for (int d = tid; d < D_; d += 256) {
        float a0 = 0.f, a1 = 0.f;
#pragma unroll
        for (int f = 0; f < FEAT; f += 2) {
            a0 += sf[f]     * wsp[f * D_ + d];
            a1 += sf[f + 1] * wsp[(f + 1) * D_ + d];
        }
        ylds[0][d] = (a0 + a1) * beta_s[d];
    }
    __syncthreads();

    // ================= fused: A(c1) ∥ D(c0) =================
    xbuf[0][w][lane]       = R0;
    xbuf[0][w][64 + lane]  = R1;
    xbuf[0][w][128 + lane] = R2;
    __syncthreads();
    p = 0;
    unsigned qd = qbase0 + w * RSTRIDE;     // D(c0): row tile*4 + w
    const v4f* y0p = (const v4f*)ylds[0];
#pragma unroll 1
    for (int tile = 0; tile < 16; ++tile) {
        if (tile < 15) {
            q += TSTRIDE;
            R0 = x4[q + lane];
            R1 = x4[q + 64 + lane];
            R2 = x4[q + 128 + lane];
        }
#pragma unroll
        for (int r = 0; r < 4; ++r) {
            v4f c0v = xbuf[p][r][lane];
            v4f c1v = xbuf[p][r][64 + lane];
            v4f c2v = xbuf[p][r][128 + lane];
            float a0 = dot4(c0v, u[0][0]) + dot4(c1v, u[0][1]) + dot4(c2v, u[0][2]);
            float a1 = dot4(c0v, u[1][0]) + dot4(c1v, u[1][1]) + dot4(c2v, u[1][2]);
            a0 += __shfl_xor(a0, 1, 64);
            a1 += __shfl_xor(a1, 1, 64);
            float val = (lane & 1) ? a1 : a0;
            val += __shfl_xor(val, 2, 64);
            val += __shfl_xor(val, 4, 64);
            val += __shfl_xor(val, 8, 64);
            val += __shfl_xor(val, 16, 64);
            val += __shfl_xor(val, 32, 64);
            if (lane < 2) vpart[tile * 4 + r][2 * w + lane] = val;
        }
        // ---- D(c0) row tile*4+w: L3-hot reload, nt store ----
        {
            v4f e0 = x4[qd + lane];
            v4f e1 = x4[qd + 64 + lane];
            v4f e2 = x4[qd + 128 + lane];
            const float m = smask[0][tile * 4 + w];
            __builtin_nontemporal_store(e0 + m * y0p[lane],        h4 + qd + lane);
            __builtin_nontemporal_store(e1 + m * y0p[64 + lane],   h4 + qd + 64 + lane);
            __builtin_nontemporal_store(e2 + m * y0p[128 + lane],  h4 + qd + 128 + lane);
            qd += TSTRIDE;
        }
        if (tile < 15) {
            xbuf[p ^ 1][w][lane]       = R0;
            xbuf[p ^ 1][w][64 + lane]  = R1;
            xbuf[p ^ 1][w][128 + lane] = R2;
        }
        __syncthreads();
        p ^= 1;
    }

    // ================= B(c1) -> sf =================
#pragma unroll
    for (int kk = 0; kk < 2; kk++) {
        const int k = w + kk * 4;
        float v = vpart[lane][k] * smask[1][lane];
        float s2  = wredux(v * v);
        float rms = sqrtf(s2 * (1.0f / T_) + EPSF);
        float vb  = 2.5f * tanhf(v / (rms + EPSF));
        const float PI = 3.14159265358979323846f;
        float ph = PI * ((float)lane + 0.5f) / (float)T_;
        float cc1 = cosf(ph), cc2 = cosf(2.0f * ph);
        float nn1 = wredux(cc1 * cc1), nn2 = wredux(cc2 * cc2);
        float S1 = wredux(vb), Sc1 = wredux(vb * cc1);
        float Sc2 = wredux(vb * cc2), Sq = wredux(vb * vb);
        if (lane == 0) {
            float* o = sf + k * 5;
            o[0] = S1 / (8.0f + EPSF);
            o[1] = Sc1 / (sqrtf(nn1) + EPSF);
            o[2] = Sc2 / (sqrtf(nn2) + EPSF);
            o[3] = S1 * (1.0f / T_);
            o[4] = sqrtf(Sq * (1.0f / T_) + EPSF);
        }
    }
    __syncthreads();

    // ================= C(c1) -> ylds[1] =================
    for (int d = tid; d < D_; d += 256) {
        float a0 = 0.f, a1 = 0.f;
#pragma unroll
        for (int f = 0; f < FEAT; f += 2) {
            a0 += sf[f]     * wsp[f * D_ + d];
            a1 += sf[f + 1] * wsp[(f + 1) * D_ + d];
        }
        ylds[1][d] = (a0 + a1) * beta_s[d];
    }
    __syncthreads();

    // ================= D(c1): rows w*16..w*16+15, pipelined =================
    const v4f* y1p = (const v4f*)ylds[1];
    const v4f y0 = y1p[lane], y1 = y1p[64 + lane], y2 = y1p[128 + lane];
    unsigned qD = qbase1 + (unsigned)(w * 16) * RSTRIDE;
    v4f d0 = x4[qD + lane];
    v4f d1 = x4[qD + 64 + lane];
    v4f d2 = x4[qD + 128 + lane];
#pragma unroll 1
    for (int j = 0; j < 16; j++) {
        v4f e0 = d0, e1 = d1, e2 = d2;
        const unsigned qc = qD;
        if (j < 15) {
            qD += RSTRIDE;
            d0 = x4[qD + lane];
            d1 = x4[qD + 64 + lane];
            d2 = x4[qD + 128 + lane];
        }
        const float m = smask[1][w * 16 + j];
        __builtin_nontemporal_store(e0 + m * y0, h4 + qc + lane);
        __builtin_nontemporal_store(e1 + m * y1, h4 + qc + 64 + lane);
        __builtin_nontemporal_store(e2 + m * y2, h4 + qc + 128 + lane);
    }
}

extern "C" void kernel_launch(void* const* d_in, const int* in_sizes, int n_in,
                              void* d_out, int out_size, void* d_ws, size_t ws_size,
                              hipStream_t stream) {
    const float* x    = (const float*)d_in[0];
    const float* mask = (const float*)d_in[1];
    const float* pw   = (const float*)d_in[2];
    const float* wraw = (const float*)d_in[3];
    const float* beta = (const float*)d_in[4];

    float* h    = (float*)d_out;
    float* wout = h + HSIZE;
    float* beta_s = (float*)d_ws;   // [768]

    hipLaunchKernelGGL(k_wsp, dim3((FEAT * D_ + 255) / 256), dim3(256), 0, stream,
                       wraw, beta, wout, beta_s);
    hipLaunchKernelGGL(k_fused, dim3(BN / 2), dim3(256), 0, stream,
                       x, mask, pw, wout, beta_s, h);
}

// Round 15
// 151.195 us; speedup vs baseline: 1.3667x; 1.3667x over previous
//
#include <hip/hip_runtime.h>
#include <math.h>

#define B_ 8
#define T_ 64
#define N_ 196
#define D_ 768
#define K_ 8
#define FEAT 40
#define EPSF 1e-6f

constexpr int BN = B_ * N_;                        // 1568
constexpr int ROWS = B_ * T_ * N_;                 // 100352
constexpr long long HSIZE = (long long)ROWS * D_;  // 77070336
constexpr int QPR = D_ / 4;                        // 192 float4 per row
constexpr unsigned RSTRIDE = (unsigned)N_ * QPR;   // 37632 v4f per t-step

typedef float v4f __attribute__((ext_vector_type(4)));

__device__ __forceinline__ float wredux(float v) {
#pragma unroll
    for (int off = 32; off > 0; off >>= 1)
        v += __shfl_xor(v, off, 64);
    return v;
}

__device__ __forceinline__ float dot4(v4f a, v4f b) {
    return a.x * b.x + a.y * b.y + a.z * b.z + a.w * b.w;
}

// W = softplus(W_raw) -> d_out tail;  beta_s = sigmoid(beta) -> ws
__global__ __launch_bounds__(256) void k_wsp(const float* __restrict__ wraw,
                                             const float* __restrict__ beta,
                                             float* __restrict__ wout,
                                             float* __restrict__ beta_s) {
    int i = blockIdx.x * blockDim.x + threadIdx.x;
    if (i < FEAT * D_) {
        float xw = wraw[i];
        wout[i] = fmaxf(xw, 0.0f) + log1pf(expf(-fabsf(xw)));
    }
    if (i < D_) beta_s[i] = 1.0f / (1.0f + expf(-beta[i]));
}

// Fused, one block per (b,n), 256 threads = 4 waves. Round-12 structure
// with SINGLE-buffered 12 KB x-tile (reg prefetch R0-R2 provides the
// pipelining) -> LDS 18.4 KB -> ~8 resident blocks/CU (round-12: 30.7 KB,
// ~3 blocks). NO launch_bounds min-waves: allocator's natural ~56 VGPR is
// the sweet spot (round-13 lesson: forcing 8 waves/EU gave VGPR=32 and
// destroyed the pipeline; occupancy must come from LDS, not reg caps).
__global__ __launch_bounds__(256)
void k_fused(const float* __restrict__ x,
             const float* __restrict__ mask,
             const float* __restrict__ pw,
             const float* __restrict__ wsp,
             const float* __restrict__ beta_s,
             float* __restrict__ h) {
    __shared__ v4f   xbuf[4][QPR];        // 12 KB x tile (single buffer)
    __shared__ float vpart[T_][K_ + 1];   // pad: odd stride, conflict-free
    __shared__ float sf[FEAT];
    __shared__ float ylds[D_];
    __shared__ float smask[T_];

    const int tid  = threadIdx.x;
    const int lane = tid & 63;
    const int w    = tid >> 6;
    const int bn   = blockIdx.x;
    const int b    = bn / N_;
    const int n    = bn - b * N_;

    // u-slice for this wave's two k's: 6 v4f = 24 VGPRs, loop-invariant
    v4f u[2][3];
#pragma unroll
    for (int kk = 0; kk < 2; kk++)
#pragma unroll
        for (int c = 0; c < 3; c++)
            u[kk][c] = *(const v4f*)(pw + (2 * w + kk) * D_ + c * 256 + lane * 4);

    if (tid < T_) smask[tid] = mask[(b * T_ + tid) * N_ + n];

    // ---- Phase A: 16 tiles x 4 rows; wave w stages row w of each tile ----
    const v4f* x4 = (const v4f*)x;
    const unsigned TSTRIDE = 4 * RSTRIDE;
    unsigned q = (unsigned)((b * T_ + w) * N_ + n) * QPR;
    v4f R0 = x4[q + lane], R1 = x4[q + 64 + lane], R2 = x4[q + 128 + lane];
#pragma unroll 1
    for (int tile = 0; tile < 16; ++tile) {
        __syncthreads();   // previous tile's LDS reads done -> safe overwrite
        xbuf[w][lane]       = R0;
        xbuf[w][64 + lane]  = R1;
        xbuf[w][128 + lane] = R2;
        if (tile < 15) {   // issue next tile's loads; land under compute
            q += TSTRIDE;
            R0 = x4[q + lane];
            R1 = x4[q + 64 + lane];
            R2 = x4[q + 128 + lane];
        }
        __syncthreads();   // ds_writes visible
#pragma unroll
        for (int r = 0; r < 4; ++r) {
            v4f c0 = xbuf[r][lane];
            v4f c1 = xbuf[r][64 + lane];
            v4f c2 = xbuf[r][128 + lane];
            float a0 = dot4(c0, u[0][0]) + dot4(c1, u[0][1]) + dot4(c2, u[0][2]);
            float a1 = dot4(c0, u[1][0]) + dot4(c1, u[1][1]) + dot4(c2, u[1][2]);
            a0 += __shfl_xor(a0, 1, 64);
            a1 += __shfl_xor(a1, 1, 64);
            float val = (lane & 1) ? a1 : a0;
            val += __shfl_xor(val, 2, 64);
            val += __shfl_xor(val, 4, 64);
            val += __shfl_xor(val, 8, 64);
            val += __shfl_xor(val, 16, 64);
            val += __shfl_xor(val, 32, 64);
            if (lane < 2) vpart[tile * 4 + r][2 * w + lane] = val;
        }
    }
    __syncthreads();

    // ---- Phase B: wave w owns k = w and k = w+4; lane = t ----
#pragma unroll
    for (int kk = 0; kk < 2; kk++) {
        const int k = w + kk * 4;
        float v = vpart[lane][k] * smask[lane];
        float s2  = wredux(v * v);
        float rms = sqrtf(s2 * (1.0f / T_) + EPSF);
        float vb  = 2.5f * tanhf(v / (rms + EPSF));
        const float PI = 3.14159265358979323846f;
        float ph = PI * ((float)lane + 0.5f) / (float)T_;
        float c1 = cosf(ph), c2 = cosf(2.0f * ph);
        float n1 = wredux(c1 * c1), n2 = wredux(c2 * c2);
        float S1 = wredux(vb), Sc1 = wredux(vb * c1);
        float Sc2 = wredux(vb * c2), Sq = wredux(vb * vb);
        if (lane == 0) {
            float* o = sf + k * 5;
            o[0] = S1 / (8.0f + EPSF);
            o[1] = Sc1 / (sqrtf(n1) + EPSF);
            o[2] = Sc2 / (sqrtf(n2) + EPSF);
            o[3] = S1 * (1.0f / T_);
            o[4] = sqrtf(Sq * (1.0f / T_) + EPSF);
        }
    }
    __syncthreads();

    // ---- Phase C: ylds[d] = beta_s[d] * sum_f sf[f]*wsp[f][d] (L2-hot) ----
    for (int d = tid; d < D_; d += 256) {
        float a0 = 0.f, a1 = 0.f;
#pragma unroll
        for (int f = 0; f < FEAT; f += 2) {
            a0 += sf[f]     * wsp[f * D_ + d];
            a1 += sf[f + 1] * wsp[(f + 1) * D_ + d];
        }
        ylds[d] = (a0 + a1) * beta_s[d];
    }
    __syncthreads();

    // ---- Phase D: rows t = w*16..w*16+15; x reload L3-hot; nt stores ----
    const v4f* y4 = (const v4f*)ylds;
    const v4f y0 = y4[lane], y1 = y4[64 + lane], y2 = y4[128 + lane];
    v4f* h4 = (v4f*)h;
    unsigned qD = (unsigned)((b * T_ + w * 16) * N_ + n) * QPR;
    v4f d0 = __builtin_nontemporal_load(x4 + qD + lane);
    v4f d1 = __builtin_nontemporal_load(x4 + qD + 64 + lane);
    v4f d2 = __builtin_nontemporal_load(x4 + qD + 128 + lane);
#pragma unroll 1
    for (int j = 0; j < 16; j++) {
        v4f c0 = d0, c1 = d1, c2 = d2;
        const unsigned qc = qD;
        if (j < 15) {
            qD += RSTRIDE;
            d0 = __builtin_nontemporal_load(x4 + qD + lane);
            d1 = __builtin_nontemporal_load(x4 + qD + 64 + lane);
            d2 = __builtin_nontemporal_load(x4 + qD + 128 + lane);
        }
        const float m = smask[w * 16 + j];
        __builtin_nontemporal_store(c0 + m * y0, h4 + qc + lane);
        __builtin_nontemporal_store(c1 + m * y1, h4 + qc + 64 + lane);
        __builtin_nontemporal_store(c2 + m * y2, h4 + qc + 128 + lane);
    }
}

extern "C" void kernel_launch(void* const* d_in, const int* in_sizes, int n_in,
                              void* d_out, int out_size, void* d_ws, size_t ws_size,
                              hipStream_t stream) {
    const float* x    = (const float*)d_in[0];
    const float* mask = (const float*)d_in[1];
    const float* pw   = (const float*)d_in[2];
    const float* wraw = (const float*)d_in[3];
    const float* beta = (const float*)d_in[4];

    float* h    = (float*)d_out;
    float* wout = h + HSIZE;
    float* beta_s = (float*)d_ws;   // [768]

    hipLaunchKernelGGL(k_wsp, dim3((FEAT * D_ + 255) / 256), dim3(256), 0, stream,
                       wraw, beta, wout, beta_s);
    hipLaunchKernelGGL(k_fused, dim3(BN), dim3(256), 0, stream,
                       x, mask, pw, wout, beta_s, h);
}